// Round 8
// baseline (186.803 us; speedup 1.0000x reference)
//
#include <hip/hip_runtime.h>
#include <hip/hip_bf16.h>

#define NB   32      // batch N
#define NRR  48      // rows NR
#define TT   2048    // temporal length T
#define DD   256     // d_model
#define QQ   32      // query points
#define ROWS (NB * NRR)   // 1536 total rows
#define NXCD 8

typedef float f32x4 __attribute__((ext_vector_type(4)));

// Phased locality at FULL grid width (R7 retry without the concurrency loss).
// 1536 blocks; hardware XCD x = bid&7. The 192 blocks on XCD x split into
// (half, g, r); each block runs TWO phases of 16 query points:
//   phase 0: row n0 = 2x+g   -> XCD x's live gather set = 2 slices = 4 MiB ~ L2
//   phase 1: row n1 = 16+2x+g
// Identical per-block cost keeps phases loosely synchronized; per-XCD L2
// working set stays ~4 MiB instead of 8 (R6 thrashed ~50% to L3).
// __launch_bounds__(256,6) caps VGPR ~85 so all 6 blocks/CU stay resident.
__global__ __launch_bounds__(256, 6) void pd_kernel(
    const float* __restrict__ pro,     // (N, NR, D)
    const float* __restrict__ feat,    // (N, T, D)
    const float* __restrict__ sp,      // (N, NR, Q)
    const float* __restrict__ w_bo, const float* __restrict__ b_bo,
    const float* __restrict__ w_co, const float* __restrict__ b_co,
    const float* __restrict__ w_bw, const float* __restrict__ b_bw,
    const float* __restrict__ w_cw, const float* __restrict__ b_cw,
    float* __restrict__ out)           // (Q, ROWS, D)
{
    const int bid  = blockIdx.x;
    const int xcd  = bid & (NXCD - 1);     // hardware XCD of this block
    const int t    = bid >> 3;             // 0..191 within XCD
    const int half = t & 1;                // which 16-q half this block owns
    const int u    = t >> 1;               // 0..95
    const int g    = u / NRR;              // 0 or 1: slice within the pair
    const int r    = u % NRR;              // row within slice
    const int lane = threadIdx.x & 63;
    const int wv   = threadIdx.x >> 6;     // wave 0..3
    const int d4   = lane << 2;            // channel base (float4 per lane)
    const float inv_w = 1.0f / 2048.0f;

#pragma unroll 1   // phases must stay separate (that's the locality)
    for (int p = 0; p < 2; ++p) {
        const int n   = 16 * p + 2 * xcd + g;
        const int row = n * NRR + r;

        // ---- 16 dot products of pro[row,:] with the 4x4 weight rows ----
        const f32x4 pv = *reinterpret_cast<const f32x4*>(pro + (size_t)row * DD + d4);

        float acc[16];
#pragma unroll
        for (int s = 0; s < 4; ++s) {
            f32x4 w;
            w = *reinterpret_cast<const f32x4*>(w_bo + s * DD + d4);
            acc[s]      = pv.x * w.x + pv.y * w.y + pv.z * w.z + pv.w * w.w;
            w = *reinterpret_cast<const f32x4*>(w_co + s * DD + d4);
            acc[4 + s]  = pv.x * w.x + pv.y * w.y + pv.z * w.z + pv.w * w.w;
            w = *reinterpret_cast<const f32x4*>(w_bw + s * DD + d4);
            acc[8 + s]  = pv.x * w.x + pv.y * w.y + pv.z * w.z + pv.w * w.w;
            w = *reinterpret_cast<const f32x4*>(w_cw + s * DD + d4);
            acc[12 + s] = pv.x * w.x + pv.y * w.y + pv.z * w.z + pv.w * w.w;
        }
#pragma unroll
        for (int st = 1; st < 64; st <<= 1) {
#pragma unroll
            for (int k = 0; k < 16; ++k)
                acc[k] += __shfl_xor(acc[k], st, 64);
        }

        float boff[4], coff[4], bw[4], cw[4];
#pragma unroll
        for (int s = 0; s < 4; ++s) {
            boff[s] = (acc[s]      + b_bo[s]) * inv_w;   // hoisted /WINDOW
            coff[s] = (acc[4 + s]  + b_co[s]) * inv_w;
            bw[s]   = acc[8 + s]  + b_bw[s];
            cw[s]   = acc[12 + s] + b_cw[s];
        }
        {   // softmax over s (max-subtracted), fold in the 0.5 row weight
            float mb = fmaxf(fmaxf(bw[0], bw[1]), fmaxf(bw[2], bw[3]));
            float mc = fmaxf(fmaxf(cw[0], cw[1]), fmaxf(cw[2], cw[3]));
            float sb = 0.f, sc = 0.f;
#pragma unroll
            for (int s = 0; s < 4; ++s) { bw[s] = expf(bw[s] - mb); sb += bw[s]; }
#pragma unroll
            for (int s = 0; s < 4; ++s) { cw[s] = expf(cw[s] - mc); sc += cw[s]; }
            const float rb = 0.5f / sb, rc = 0.5f / sc;
#pragma unroll
            for (int s = 0; s < 4; ++s) { bw[s] *= rb; cw[s] *= rc; }
        }

        // ---- gather + mix: wave wv owns q = 16*half + 4*wv .. +3 (2 q-pairs) ----
        const float* fnrow = feat + (size_t)n * (TT * DD);   // wave-uniform base
        const float* spr   = sp + (size_t)row * QQ;
        const int    qbase = (half << 4) + (wv << 2);

#pragma unroll
        for (int j2 = 0; j2 < 2; ++j2) {
            int   idx[16];
            float cc[16];
#pragma unroll
            for (int h = 0; h < 2; ++h) {
                const int   q     = qbase + (j2 << 1) + h;
                const bool  isB   = (q < 4);             // wave-uniform (4-q aligned)
                const float point = spr[q];
#pragma unroll
                for (int s = 0; s < 4; ++s) {
                    const float off = isB ? boff[s] : coff[s];
                    const float loc = fminf(fmaxf(point + off, 0.f), 1.f);
                    const float px  = loc * (float)TT - 0.5f;
                    const float x0f = floorf(px);
                    const float w1  = px - x0f;          // right-neighbor weight
                    const int   x0  = (int)x0f;          // in [-1, 2047]
                    const int   x0c = x0 < 0 ? 0 : x0;
                    const int   x1c = x0 + 1 > TT - 1 ? TT - 1 : x0 + 1;
                    const float wgt = isB ? bw[s] : cw[s];
                    const int   k   = (h << 3) + (s << 1);
                    cc[k]     = (x0 >= 0)     ? wgt * (1.f - w1) : 0.f;
                    cc[k + 1] = (x0 + 1 < TT) ? wgt * w1         : 0.f;
                    idx[k]     = __builtin_amdgcn_readfirstlane(x0c) * DD;
                    idx[k + 1] = __builtin_amdgcn_readfirstlane(x1c) * DD;
                }
            }

            f32x4 gv[16];
#pragma unroll
            for (int k = 0; k < 16; ++k)
                gv[k] = *reinterpret_cast<const f32x4*>(fnrow + idx[k] + d4);

            // Pin the schedule: all 16 loads issued before any consumer.
            __builtin_amdgcn_sched_barrier(0);

            f32x4 o0 = {0.f, 0.f, 0.f, 0.f};
            f32x4 o1 = {0.f, 0.f, 0.f, 0.f};
#pragma unroll
            for (int k = 0; k < 8; ++k)  o0 += cc[k] * gv[k];
#pragma unroll
            for (int k = 8; k < 16; ++k) o1 += cc[k] * gv[k];

            const int q0 = qbase + (j2 << 1);
            __builtin_nontemporal_store(o0,
                reinterpret_cast<f32x4*>(out + ((size_t)q0 * ROWS + row) * DD + d4));
            __builtin_nontemporal_store(o1,
                reinterpret_cast<f32x4*>(out + ((size_t)(q0 + 1) * ROWS + row) * DD + d4));
        }
    }
}

extern "C" void kernel_launch(void* const* d_in, const int* in_sizes, int n_in,
                              void* d_out, int out_size, void* d_ws, size_t ws_size,
                              hipStream_t stream) {
    const float* pro  = (const float*)d_in[0];
    const float* feat = (const float*)d_in[1];
    const float* sp   = (const float*)d_in[2];
    const float* w_bo = (const float*)d_in[3];
    const float* b_bo = (const float*)d_in[4];
    const float* w_co = (const float*)d_in[5];
    const float* b_co = (const float*)d_in[6];
    const float* w_bw = (const float*)d_in[7];
    const float* b_bw = (const float*)d_in[8];
    const float* w_cw = (const float*)d_in[9];
    const float* b_cw = (const float*)d_in[10];
    float* out = (float*)d_out;

    pd_kernel<<<ROWS, 256, 0, stream>>>(
        pro, feat, sp, w_bo, b_bo, w_co, b_co, w_bw, b_bw, w_cw, b_cw, out);
}

// Round 9
// 29.643 us; speedup vs baseline: 6.3017x; 6.3017x over previous
//
#include <hip/hip_runtime.h>
#include <hip/hip_bf16.h>

#define NB   32      // batch N
#define NRR  48      // rows NR
#define TT   2048    // temporal length T
#define DD   256     // d_model
#define QQ   32      // query points
#define ROWS (NB * NRR)   // 1536 total rows
#define NXCD 8

typedef float f32x4 __attribute__((ext_vector_type(4)));

// Occupancy-first variant. 3072 blocks x 128 threads (2 independent waves,
// no __syncthreads). Block b -> (row, half): XCD swizzle keeps same-n blocks
// on one XCD. Each wave covers all 256 channels as f32x4 (lane*4), computes
// the 16 tiny dots redundantly (wave butterfly), and owns 8 query points.
// Gathers: single-q bursts of 8 clamped coefficient-masked loads (32 VGPR
// live) + sched_barrier -> MLP 8 per wave; concurrency from ~28-32 waves/CU
// instead of R6's 24x16 (VGPR 68 capped waves). NO min-occupancy bound
// (R8: bounds+big burst => scratch spills, 6x memory traffic).
__global__ __launch_bounds__(128) void pd_kernel(
    const float* __restrict__ pro,     // (N, NR, D)
    const float* __restrict__ feat,    // (N, T, D)
    const float* __restrict__ sp,      // (N, NR, Q)
    const float* __restrict__ w_bo, const float* __restrict__ b_bo,
    const float* __restrict__ w_co, const float* __restrict__ b_co,
    const float* __restrict__ w_bw, const float* __restrict__ b_bw,
    const float* __restrict__ w_cw, const float* __restrict__ b_cw,
    float* __restrict__ out)           // (Q, ROWS, D)
{
    const int bid  = blockIdx.x;
    const int xcd  = bid & (NXCD - 1);       // hardware XCD
    const int t    = bid >> 3;               // 0..383 within XCD
    const int half = t & 1;                  // which 16-q half
    const int row  = xcd * (ROWS / NXCD) + (t >> 1);   // n in [4*xcd, 4*xcd+4)
    const int n    = row / NRR;
    const int lane = threadIdx.x & 63;
    const int wv   = threadIdx.x >> 6;       // wave 0..1
    const int d4   = lane << 2;              // channel base (f32x4 per lane)
    const float inv_w = 1.0f / 2048.0f;

    // ---- 16 dot products of pro[row,:] with the 4x4 weight rows ----
    const f32x4 pv = *reinterpret_cast<const f32x4*>(pro + (size_t)row * DD + d4);

    float acc[16];
#pragma unroll
    for (int s = 0; s < 4; ++s) {
        f32x4 w;
        w = *reinterpret_cast<const f32x4*>(w_bo + s * DD + d4);
        acc[s]      = pv.x * w.x + pv.y * w.y + pv.z * w.z + pv.w * w.w;
        w = *reinterpret_cast<const f32x4*>(w_co + s * DD + d4);
        acc[4 + s]  = pv.x * w.x + pv.y * w.y + pv.z * w.z + pv.w * w.w;
        w = *reinterpret_cast<const f32x4*>(w_bw + s * DD + d4);
        acc[8 + s]  = pv.x * w.x + pv.y * w.y + pv.z * w.z + pv.w * w.w;
        w = *reinterpret_cast<const f32x4*>(w_cw + s * DD + d4);
        acc[12 + s] = pv.x * w.x + pv.y * w.y + pv.z * w.z + pv.w * w.w;
    }
    // 64-lane butterfly reduce; every lane ends with all 16 dot values.
#pragma unroll
    for (int st = 1; st < 64; st <<= 1) {
#pragma unroll
        for (int k = 0; k < 16; ++k)
            acc[k] += __shfl_xor(acc[k], st, 64);
    }

    float boff[4], coff[4], bw[4], cw[4];
#pragma unroll
    for (int s = 0; s < 4; ++s) {
        boff[s] = (acc[s]      + b_bo[s]) * inv_w;   // offset/WINDOW hoisted
        coff[s] = (acc[4 + s]  + b_co[s]) * inv_w;
        bw[s]   = acc[8 + s]  + b_bw[s];
        cw[s]   = acc[12 + s] + b_cw[s];
    }
    {   // softmax over s (max-subtracted), fold in the 0.5 row weight
        float mb = fmaxf(fmaxf(bw[0], bw[1]), fmaxf(bw[2], bw[3]));
        float mc = fmaxf(fmaxf(cw[0], cw[1]), fmaxf(cw[2], cw[3]));
        float sb = 0.f, sc = 0.f;
#pragma unroll
        for (int s = 0; s < 4; ++s) { bw[s] = expf(bw[s] - mb); sb += bw[s]; }
#pragma unroll
        for (int s = 0; s < 4; ++s) { cw[s] = expf(cw[s] - mc); sc += cw[s]; }
        const float rb = 0.5f / sb, rc = 0.5f / sc;
#pragma unroll
        for (int s = 0; s < 4; ++s) { bw[s] *= rb; cw[s] *= rc; }
    }

    // ---- gather + mix: this wave owns q = 16*half + 8*wv + j, j=0..7 ----
    const float* fnrow = feat + (size_t)n * (TT * DD);   // wave-uniform base
    const float* spr   = sp + (size_t)row * QQ;
    const int    qbase = (half << 4) + (wv << 3);

#pragma unroll
    for (int j = 0; j < 8; ++j) {
        const int   q     = qbase + j;
        const bool  isB   = (q < 4);             // wave-uniform
        const float point = spr[q];

        int   idx[8];
        float cc[8];
#pragma unroll
        for (int s = 0; s < 4; ++s) {
            const float off = isB ? boff[s] : coff[s];
            const float loc = fminf(fmaxf(point + off, 0.f), 1.f);
            const float px  = loc * (float)TT - 0.5f;
            const float x0f = floorf(px);
            const float w1  = px - x0f;          // right-neighbor weight
            const int   x0  = (int)x0f;          // in [-1, 2047]
            const int   x0c = x0 < 0 ? 0 : x0;
            const int   x1c = x0 + 1 > TT - 1 ? TT - 1 : x0 + 1;
            const float wgt = isB ? bw[s] : cw[s];
            cc[2 * s]     = (x0 >= 0)     ? wgt * (1.f - w1) : 0.f;
            cc[2 * s + 1] = (x0 + 1 < TT) ? wgt * w1         : 0.f;
            idx[2 * s]     = __builtin_amdgcn_readfirstlane(x0c) * DD;
            idx[2 * s + 1] = __builtin_amdgcn_readfirstlane(x1c) * DD;
        }

        f32x4 gv[8];
#pragma unroll
        for (int k = 0; k < 8; ++k)
            gv[k] = *reinterpret_cast<const f32x4*>(fnrow + idx[k] + d4);

        // Pin: all 8 loads issued before any consumer (MLP=8).
        __builtin_amdgcn_sched_barrier(0);

        f32x4 o = {0.f, 0.f, 0.f, 0.f};
#pragma unroll
        for (int k = 0; k < 8; ++k)
            o += cc[k] * gv[k];

        __builtin_nontemporal_store(o,
            reinterpret_cast<f32x4*>(out + ((size_t)q * ROWS + row) * DD + d4));
    }
}

extern "C" void kernel_launch(void* const* d_in, const int* in_sizes, int n_in,
                              void* d_out, int out_size, void* d_ws, size_t ws_size,
                              hipStream_t stream) {
    const float* pro  = (const float*)d_in[0];
    const float* feat = (const float*)d_in[1];
    const float* sp   = (const float*)d_in[2];
    const float* w_bo = (const float*)d_in[3];
    const float* b_bo = (const float*)d_in[4];
    const float* w_co = (const float*)d_in[5];
    const float* b_co = (const float*)d_in[6];
    const float* w_bw = (const float*)d_in[7];
    const float* b_bw = (const float*)d_in[8];
    const float* w_cw = (const float*)d_in[9];
    const float* b_cw = (const float*)d_in[10];
    float* out = (float*)d_out;

    pd_kernel<<<ROWS * 2, 128, 0, stream>>>(
        pro, feat, sp, w_bo, b_bo, w_co, b_co, w_bw, b_bw, w_cw, b_cw, out);
}